// Round 4
// baseline (2290.766 us; speedup 1.0000x reference)
//
#include <hip/hip_runtime.h>
#include <hip/hip_bf16.h>

// Problem constants (BoW mini-GPT forward): B=4 T=2048 V=50257 C=512 H=2048
#define B_    4
#define T_    2048
#define V_    50257
#define C_    512
#define H_    2048
#define BT_   8192
#define VPAD_ 51200   // 200*256, divisible by 1024
#define MB_   ((size_t)1 << 20)

typedef unsigned short u16;
typedef __attribute__((ext_vector_type(8))) short bf16x8;
typedef __attribute__((ext_vector_type(4))) float f32x4;
typedef __attribute__((ext_vector_type(4), aligned(16))) float f32x4a;
typedef __attribute__((ext_vector_type(4), aligned(4))) float f32x4u;
typedef const __attribute__((address_space(1))) unsigned gu32;
typedef __attribute__((address_space(3))) unsigned su32;

__device__ __forceinline__ u16 f2bf(float f) {
    unsigned u = __builtin_bit_cast(unsigned, f);
    u = u + 0x7fffu + ((u >> 16) & 1u);   // round-to-nearest-even
    return (u16)(u >> 16);
}

// ---------------- embedding + causal BoW (3 small kernels) --------------------------
__global__ void emb_kernel(const int* __restrict__ x, const float* __restrict__ wte,
                           const float* __restrict__ wpe, float* __restrict__ emb,
                           float* __restrict__ S)
{
    int bid = blockIdx.x;
    int cg  = bid & 1;
    int ch  = (bid >> 1) & 15;
    int b   = bid >> 5;
    int c   = cg * 256 + threadIdx.x;
    __shared__ int toks[128];
    if (threadIdx.x < 128) toks[threadIdx.x] = x[b * T_ + ch * 128 + threadIdx.x];
    __syncthreads();
    float sum = 0.f;
    #pragma unroll 4
    for (int tt = 0; tt < 128; ++tt) {
        int t = ch * 128 + tt;
        float e = wte[(size_t)toks[tt] * C_ + c] + wpe[(size_t)t * C_ + c];
        emb[(size_t)(b * T_ + t) * C_ + c] = e;
        sum += e;
    }
    S[(b * 16 + ch) * C_ + c] = sum;
}

__global__ void scan_kernel(const float* __restrict__ S, float* __restrict__ P)
{
    int idx = blockIdx.x * 256 + threadIdx.x;   // 0..2047
    int b = idx >> 9, c = idx & 511;
    float run = 0.f;
    #pragma unroll
    for (int ch = 0; ch < 16; ++ch) {
        P[(b * 16 + ch) * C_ + c] = run;
        run += S[(b * 16 + ch) * C_ + c];
    }
}

__global__ void bow_kernel(const float* __restrict__ emb, const float* __restrict__ P,
                           float* __restrict__ h1f, u16* __restrict__ h1b)
{
    int bid = blockIdx.x;
    int cg  = bid & 1;
    int ch  = (bid >> 1) & 15;
    int b   = bid >> 5;
    int c   = cg * 256 + threadIdx.x;
    float run = P[(b * 16 + ch) * C_ + c];
    #pragma unroll 4
    for (int tt = 0; tt < 128; ++tt) {
        int t = ch * 128 + tt;
        size_t idx = (size_t)(b * T_ + t) * C_ + c;
        float e = emb[idx];
        run += e;
        float h = e + run / (float)(t + 1);
        h1f[idx] = h;
        h1b[idx] = f2bf(h);
    }
}

// transpose + fp32->bf16 convert: Wt[v][k] = W[k][colStart+v], zero-pad v>=N.
__global__ void tconv_kernel(const float* __restrict__ W, u16* __restrict__ Wt,
                             int K, int N, int colStart, int nCols)
{
    __shared__ float tile[32][33];
    int v0 = blockIdx.x * 32, k0 = blockIdx.y * 32;
    int tx = threadIdx.x, ty = threadIdx.y;
    #pragma unroll
    for (int r = 0; r < 4; ++r) {
        int k = k0 + ty + r * 8;
        int v = colStart + v0 + tx;
        tile[ty + r * 8][tx] = (v < N) ? W[(size_t)k * N + v] : 0.f;
    }
    __syncthreads();
    #pragma unroll
    for (int r = 0; r < 4; ++r) {
        int vl = ty + r * 8;
        Wt[(size_t)(v0 + vl) * K + k0 + tx] = f2bf(tile[tx][vl]);
    }
}

__global__ void padb_kernel(const float* __restrict__ b, float* __restrict__ bp)
{
    int i = blockIdx.x * 256 + threadIdx.x;
    if (i < VPAD_) bp[i] = (i < V_) ? b[i] : 0.f;
}

// ---------------- MLP bf16 MFMA GEMM (128x128x64, proven path) ----------------------
// EPI 0: outB = bf16(tanh(acc + bias[n]))          EPI 1: outB = bf16(acc+bias+resid)
template <int EPI>
__global__ __launch_bounds__(256, 3)
void gemm_kernel(const u16* __restrict__ A, const u16* __restrict__ Bt,
                 int M, int N, int K,
                 const float* __restrict__ bias, const float* __restrict__ resid,
                 u16* __restrict__ outB, int ldOut)
{
    __shared__ char smem[32768];
    const int tid  = threadIdx.x;
    const int wid  = tid >> 6;
    const int lane = tid & 63;
    const int wm   = wid >> 1, wn = wid & 1;
    const int lr   = lane & 15;
    const int hi   = lane >> 4;

    const int NBX = N >> 7;
    const int NBY = M >> 7;
    const int nwg = NBX * NBY;
    const int per = nwg >> 3;
    const int wg  = (blockIdx.x & 7) * per + (blockIdx.x >> 3);
    const int grpSz  = NBY << 3;
    const int colgrp = wg / grpSz;
    const int baseBx = colgrp << 3;
    int wcols = NBX - baseBx; if (wcols > 8) wcols = 8;
    const int idx = wg - colgrp * grpSz;
    const int by  = idx / wcols;
    const int bx  = baseBx + idx % wcols;

    const int rowA0 = by * 128;
    const int colB0 = bx * 128;
    const int KT    = K / 64;

    auto stage = [&](int kt) {
        #pragma unroll
        for (int i = 0; i < 4; ++i) {
            int c    = i * 256 + tid;
            int row  = c >> 3;
            int slot = (c & 7) ^ (row & 7);
            const u16* ga = A  + (size_t)(rowA0 + row) * K + kt * 64 + slot * 8;
            const u16* gb = Bt + (size_t)(colB0 + row) * K + kt * 64 + slot * 8;
            int ldsOff = i * 4096 + wid * 1024;
            __builtin_amdgcn_global_load_lds((gu32*)ga, (su32*)(smem + ldsOff),         16, 0, 0);
            __builtin_amdgcn_global_load_lds((gu32*)gb, (su32*)(smem + 16384 + ldsOff), 16, 0, 0);
        }
    };

    f32x4 acc[4][4];
    #pragma unroll
    for (int m = 0; m < 4; ++m)
        #pragma unroll
        for (int n = 0; n < 4; ++n) acc[m][n] = f32x4{0.f, 0.f, 0.f, 0.f};

    for (int kt = 0; kt < KT; ++kt) {
        stage(kt);
        __syncthreads();
        #pragma unroll
        for (int ks = 0; ks < 2; ++ks) {
            bf16x8 af[4], bfr[4];
            #pragma unroll
            for (int m = 0; m < 4; ++m) {
                int row = wm * 64 + m * 16 + lr;
                int kbyte = (ks * 64 + hi * 16) ^ ((row & 7) << 4);
                af[m] = *(const bf16x8*)(smem + row * 128 + kbyte);
            }
            #pragma unroll
            for (int n = 0; n < 4; ++n) {
                int row = wn * 64 + n * 16 + lr;
                int kbyte = (ks * 64 + hi * 16) ^ ((row & 7) << 4);
                bfr[n] = *(const bf16x8*)(smem + 16384 + row * 128 + kbyte);
            }
            #pragma unroll
            for (int m = 0; m < 4; ++m)
                #pragma unroll
                for (int n = 0; n < 4; ++n)
                    acc[m][n] = __builtin_amdgcn_mfma_f32_16x16x32_bf16(af[m], bfr[n], acc[m][n], 0, 0, 0);
        }
        __syncthreads();
    }

    #pragma unroll
    for (int m = 0; m < 4; ++m) {
        #pragma unroll
        for (int n = 0; n < 4; ++n) {
            int gcol = colB0 + wn * 64 + n * 16 + lr;
            #pragma unroll
            for (int r = 0; r < 4; ++r) {
                int grow = rowA0 + wm * 64 + m * 16 + hi * 4 + r;
                float v = acc[m][n][r];
                if constexpr (EPI == 0) {
                    v = tanhf(v + bias[gcol]);
                } else {
                    v = v + bias[gcol] + resid[(size_t)grow * ldOut + gcol];
                }
                outB[(size_t)grow * ldOut + gcol] = f2bf(v);
            }
        }
    }
}

// ---------------- head: persistent M-stripe sweep, barrier-free, write-streamed -----
// Each block: A-panel 64x512 resident in LDS; sweeps nbx/4 B-tiles of 256 cols.
// Swapped MFMA (B as 1st operand) -> lane holds 4 consecutive out cols -> f32x4 nt store.
// Stores staggered 1 frag per kt so the HBM write queue never drains.

#define STORE_FRAG(n, m) do {                                                         \
    int gcol_ = pcol0 + wid * 32 + (n) * 16 + hi * 4;                                 \
    size_t off_ = (size_t)(rowA0 + (m) * 16 + lr) * V_ + gcol_;                       \
    f32x4 v_ = oreg[n][m];                                                            \
    if (gcol_ + 3 < V_) {                                                             \
        f32x4u t_ = {v_[0], v_[1], v_[2], v_[3]};                                     \
        __builtin_nontemporal_store(t_, (f32x4u*)(outF + off_));                      \
    } else {                                                                          \
        _Pragma("unroll")                                                             \
        for (int e_ = 0; e_ < 4; ++e_)                                                \
            if (gcol_ + e_ < V_) __builtin_nontemporal_store(v_[e_], outF + off_ + e_); \
    }                                                                                 \
} while (0)

#define KT_BODY(kt, CUR, NXT) {                                                       \
    if (bxl) STORE_FRAG((kt) & 1, (kt) >> 1);                                         \
    { int nb_ = ((kt) == 7) ? bxl + 1 : bxl;                                          \
      int nk_ = ((kt) + 1) & 7;                                                       \
      if (nb_ >= nbxq) nb_ = 0;                                                       \
      const char* gb_ = (const char*)Bt +                                             \
          ((size_t)(bx0 + nb_) * 256 + wid * 32 + lr) * 1024 + nk_ * 128 + hi * 16;   \
      NXT[0] = *(const bf16x8*)(gb_);                                                 \
      NXT[1] = *(const bf16x8*)(gb_ + 64);                                            \
      NXT[2] = *(const bf16x8*)(gb_ + 16384);                                         \
      NXT[3] = *(const bf16x8*)(gb_ + 16384 + 64); }                                  \
    _Pragma("unroll")                                                                 \
    for (int ks = 0; ks < 2; ++ks) {                                                  \
        bf16x8 af[4];                                                                 \
        _Pragma("unroll")                                                             \
        for (int m = 0; m < 4; ++m) {                                                 \
            int row_ = m * 16 + lr;                                                   \
            af[m] = *(const bf16x8*)(Asm + row_ * 1024 +                              \
                     ((((kt) * 8) + ks * 4 + hi) ^ (row_ & 7)) * 16);                 \
        }                                                                             \
        _Pragma("unroll")                                                             \
        for (int n = 0; n < 2; ++n)                                                   \
            _Pragma("unroll")                                                         \
            for (int m = 0; m < 4; ++m)                                               \
                acc[n][m] = __builtin_amdgcn_mfma_f32_16x16x32_bf16(                  \
                    CUR[n * 2 + ks], af[m], acc[n][m], 0, 0, 0);                      \
    }                                                                                 \
}

__global__ __launch_bounds__(512, 2)
void head_kernel(const u16* __restrict__ A, const u16* __restrict__ Bt,
                 const float* __restrict__ biasp, float* __restrict__ outF,
                 int colStart, int nbxTotal)
{
    __shared__ char Asm[65536];
    const int tid  = threadIdx.x;
    const int wid  = tid >> 6;
    const int lane = tid & 63;
    const int lr   = lane & 15;
    const int hi   = lane >> 4;

    // block -> (by, column-quarter): per-XCD lockstep B-stream sharing
    const int x    = blockIdx.x & 7;
    const int g    = blockIdx.x >> 3;             // 0..63
    const int quad = (x >> 2) * 2 + (g >> 5);     // 0..3
    const int by   = (x & 3) * 32 + (g & 31);     // 0..127
    const int nbxq = nbxTotal >> 2;
    const int bx0  = quad * nbxq;
    const int rowA0 = by * 64;

    // prologue: A-panel 64x512 bf16 -> LDS once (swizzled slot ^= row&7)
    #pragma unroll
    for (int i = 0; i < 8; ++i) {
        int d = i * 512 + tid;                    // 16B slot index 0..4095
        int row = d >> 6, slot = d & 63;
        const u16* ga = A + (size_t)(rowA0 + row) * 512 + (slot ^ (row & 7)) * 8;
        __builtin_amdgcn_global_load_lds((gu32*)ga, (su32*)(Asm + i * 8192 + wid * 1024), 16, 0, 0);
    }
    __syncthreads();                              // the only barrier

    f32x4 acc[2][4], oreg[2][4];                  // [n][m]
    #pragma unroll
    for (int n = 0; n < 2; ++n)
        #pragma unroll
        for (int m = 0; m < 4; ++m) { acc[n][m] = f32x4{0.f,0.f,0.f,0.f}; oreg[n][m] = f32x4{0.f,0.f,0.f,0.f}; }

    bf16x8 bA[4], bB[4];
    {   // preload (bxl=0, kt=0)
        const char* g0 = (const char*)Bt + ((size_t)bx0 * 256 + wid * 32 + lr) * 1024 + hi * 16;
        bA[0] = *(const bf16x8*)(g0);
        bA[1] = *(const bf16x8*)(g0 + 64);
        bA[2] = *(const bf16x8*)(g0 + 16384);
        bA[3] = *(const bf16x8*)(g0 + 16384 + 64);
    }

    int pcol0 = 0;
    for (int bxl = 0; bxl < nbxq; ++bxl) {
        KT_BODY(0, bA, bB) KT_BODY(1, bB, bA) KT_BODY(2, bA, bB) KT_BODY(3, bB, bA)
        KT_BODY(4, bA, bB) KT_BODY(5, bB, bA) KT_BODY(6, bA, bB) KT_BODY(7, bB, bA)
        int colb = colStart + (bx0 + bxl) * 256;
        #pragma unroll
        for (int n = 0; n < 2; ++n) {
            f32x4a bb = *(const f32x4a*)(biasp + colb + wid * 32 + n * 16 + hi * 4);
            #pragma unroll
            for (int m = 0; m < 4; ++m) {
                oreg[n][m] = acc[n][m] + (f32x4)bb;
                acc[n][m]  = f32x4{0.f, 0.f, 0.f, 0.f};
            }
        }
        pcol0 = colb;
    }
    // final flush
    STORE_FRAG(0, 0); STORE_FRAG(1, 0); STORE_FRAG(0, 1); STORE_FRAG(1, 1);
    STORE_FRAG(0, 2); STORE_FRAG(1, 2); STORE_FRAG(0, 3); STORE_FRAG(1, 3);
}

// ------------------------------------------------------------------------------------
extern "C" void kernel_launch(void* const* d_in, const int* in_sizes, int n_in,
                              void* d_out, int out_size, void* d_ws, size_t ws_size,
                              hipStream_t stream)
{
    const int*   x      = (const int*)  d_in[0];
    const float* wte    = (const float*)d_in[1];
    const float* wpe    = (const float*)d_in[2];
    const float* w_fc   = (const float*)d_in[3];
    const float* b_fc   = (const float*)d_in[4];
    const float* w_proj = (const float*)d_in[5];
    const float* b_proj = (const float*)d_in[6];
    const float* w_head = (const float*)d_in[7];
    const float* b_head = (const float*)d_in[8];
    float* out = (float*)d_out;

    // Scratch inside d_out (dead before the head GEMM overwrites d_out)
    char*  ob   = (char*)d_out;
    float* emb  = (float*)(ob);                    // 16 MB
    float* h1f  = (float*)(ob + 16 * MB_);         // 16 MB
    u16*   h1b  = (u16*)  (ob + 32 * MB_);         //  8 MB
    u16*   actb = (u16*)  (ob + 40 * MB_);         // 32 MB
    u16*   wfct = (u16*)  (ob + 72 * MB_);         //  2 MB
    u16*   wprt = (u16*)  (ob + 74 * MB_);         //  2 MB
    float* S    = (float*)(ob + 76 * MB_);         // 128 KB
    float* P    = (float*)(ob + 76 * MB_ + 128 * 1024);

    // ws: survives while head writes d_out
    u16*   h2b   = (u16*)d_ws;                               // 8 MB
    float* biasp = (float*)((char*)d_ws + 8 * MB_);          // 200 KB padded bias
    u16*   wht   = (u16*)((char*)d_ws + 8 * MB_ + 256 * 1024);

    long availCols = 0;
    if (ws_size > 8 * MB_ + 256 * 1024 + 2 * MB_)
        availCols = (long)((ws_size - 8 * MB_ - 256 * 1024) / (C_ * 2));
    int chunk = (int)(availCols & ~1023L);
    if (chunk < 1024)  chunk = 1024;
    if (chunk > VPAD_) chunk = VPAD_;

    // weights -> bf16 transposed (N-major, K-contiguous)
    tconv_kernel<<<dim3(H_ / 32, C_ / 32), dim3(32, 8), 0, stream>>>(w_fc,   wfct, C_, H_, 0, H_);
    tconv_kernel<<<dim3(C_ / 32, H_ / 32), dim3(32, 8), 0, stream>>>(w_proj, wprt, H_, C_, 0, C_);
    padb_kernel<<<VPAD_ / 256, 256, 0, stream>>>(b_head, biasp);

    // embedding + causal BoW
    emb_kernel <<<128, 256, 0, stream>>>(x, wte, wpe, emb, S);
    scan_kernel<<<8,   256, 0, stream>>>(S, P);
    bow_kernel <<<128, 256, 0, stream>>>(emb, P, h1f, h1b);

    // MLP
    gemm_kernel<0><<<(H_ / 128) * (BT_ / 128), 256, 0, stream>>>(
        h1b, wfct, BT_, H_, C_, b_fc, nullptr, actb, H_);
    gemm_kernel<1><<<(C_ / 128) * (BT_ / 128), 256, 0, stream>>>(
        actb, wprt, BT_, C_, H_, b_proj, h1f, h2b, C_);

    // head: V in ws-sized column chunks (usually one)
    for (int cs = 0; cs < VPAD_; cs += chunk) {
        int nc = VPAD_ - cs < chunk ? VPAD_ - cs : chunk;
        tconv_kernel<<<dim3(nc / 32, C_ / 32), dim3(32, 8), 0, stream>>>(
            w_head, wht, C_, V_, cs, nc);
        head_kernel<<<512, 512, 0, stream>>>(h2b, wht, biasp, out, cs, nc / 256);
    }
}

// Round 5
// 924.421 us; speedup vs baseline: 2.4781x; 2.4781x over previous
//
#include <hip/hip_runtime.h>
#include <hip/hip_bf16.h>

// Problem constants (BoW mini-GPT forward): B=4 T=2048 V=50257 C=512 H=2048
#define B_    4
#define T_    2048
#define V_    50257
#define C_    512
#define H_    2048
#define BT_   8192
#define VPAD_ 50432   // 197*256
#define MB_   ((size_t)1 << 20)

typedef unsigned short u16;
typedef __attribute__((ext_vector_type(8))) short bf16x8;
typedef __attribute__((ext_vector_type(4))) float f32x4;
typedef __attribute__((ext_vector_type(4), aligned(16))) float f32x4a;
typedef const __attribute__((address_space(1))) unsigned gu32;
typedef __attribute__((address_space(3))) unsigned su32;

__device__ __forceinline__ u16 f2bf(float f) {
    unsigned u = __builtin_bit_cast(unsigned, f);
    u = u + 0x7fffu + ((u >> 16) & 1u);   // round-to-nearest-even
    return (u16)(u >> 16);
}

// ---------------- embedding + causal BoW (3 small kernels) --------------------------
__global__ void emb_kernel(const int* __restrict__ x, const float* __restrict__ wte,
                           const float* __restrict__ wpe, float* __restrict__ emb,
                           float* __restrict__ S)
{
    int bid = blockIdx.x;
    int cg  = bid & 1;
    int ch  = (bid >> 1) & 15;
    int b   = bid >> 5;
    int c   = cg * 256 + threadIdx.x;
    __shared__ int toks[128];
    if (threadIdx.x < 128) toks[threadIdx.x] = x[b * T_ + ch * 128 + threadIdx.x];
    __syncthreads();
    float sum = 0.f;
    #pragma unroll 4
    for (int tt = 0; tt < 128; ++tt) {
        int t = ch * 128 + tt;
        float e = wte[(size_t)toks[tt] * C_ + c] + wpe[(size_t)t * C_ + c];
        emb[(size_t)(b * T_ + t) * C_ + c] = e;
        sum += e;
    }
    S[(b * 16 + ch) * C_ + c] = sum;
}

__global__ void scan_kernel(const float* __restrict__ S, float* __restrict__ P)
{
    int idx = blockIdx.x * 256 + threadIdx.x;   // 0..2047
    int b = idx >> 9, c = idx & 511;
    float run = 0.f;
    #pragma unroll
    for (int ch = 0; ch < 16; ++ch) {
        P[(b * 16 + ch) * C_ + c] = run;
        run += S[(b * 16 + ch) * C_ + c];
    }
}

__global__ void bow_kernel(const float* __restrict__ emb, const float* __restrict__ P,
                           float* __restrict__ h1f, u16* __restrict__ h1b)
{
    int bid = blockIdx.x;
    int cg  = bid & 1;
    int ch  = (bid >> 1) & 15;
    int b   = bid >> 5;
    int c   = cg * 256 + threadIdx.x;
    float run = P[(b * 16 + ch) * C_ + c];
    #pragma unroll 4
    for (int tt = 0; tt < 128; ++tt) {
        int t = ch * 128 + tt;
        size_t idx = (size_t)(b * T_ + t) * C_ + c;
        float e = emb[idx];
        run += e;
        float h = e + run / (float)(t + 1);
        h1f[idx] = h;
        h1b[idx] = f2bf(h);
    }
}

// transpose + fp32->bf16 convert: Wt[v][k] = W[k][colStart+v], zero-pad v>=N.
__global__ void tconv_kernel(const float* __restrict__ W, u16* __restrict__ Wt,
                             int K, int N, int colStart, int nCols)
{
    __shared__ float tile[32][33];
    int v0 = blockIdx.x * 32, k0 = blockIdx.y * 32;
    int tx = threadIdx.x, ty = threadIdx.y;
    #pragma unroll
    for (int r = 0; r < 4; ++r) {
        int k = k0 + ty + r * 8;
        int v = colStart + v0 + tx;
        tile[ty + r * 8][tx] = (v < N) ? W[(size_t)k * N + v] : 0.f;
    }
    __syncthreads();
    #pragma unroll
    for (int r = 0; r < 4; ++r) {
        int vl = ty + r * 8;
        Wt[(size_t)(v0 + vl) * K + k0 + tx] = f2bf(tile[tx][vl]);
    }
}

// ---------------- MLP bf16 MFMA GEMM (128x128x64, proven path) ----------------------
// EPI 0: outB = bf16(tanh(acc + bias[n]))          EPI 1: outB = bf16(acc+bias+resid)
template <int EPI>
__global__ __launch_bounds__(256, 3)
void gemm_kernel(const u16* __restrict__ A, const u16* __restrict__ Bt,
                 int M, int N, int K,
                 const float* __restrict__ bias, const float* __restrict__ resid,
                 u16* __restrict__ outB, int ldOut)
{
    __shared__ char smem[32768];
    const int tid  = threadIdx.x;
    const int wid  = tid >> 6;
    const int lane = tid & 63;
    const int wm   = wid >> 1, wn = wid & 1;
    const int lr   = lane & 15;
    const int hi   = lane >> 4;

    const int NBX = N >> 7;
    const int NBY = M >> 7;
    const int nwg = NBX * NBY;
    const int per = nwg >> 3;
    const int wg  = (blockIdx.x & 7) * per + (blockIdx.x >> 3);
    const int grpSz  = NBY << 3;
    const int colgrp = wg / grpSz;
    const int baseBx = colgrp << 3;
    int wcols = NBX - baseBx; if (wcols > 8) wcols = 8;
    const int idx = wg - colgrp * grpSz;
    const int by  = idx / wcols;
    const int bx  = baseBx + idx % wcols;

    const int rowA0 = by * 128;
    const int colB0 = bx * 128;
    const int KT    = K / 64;

    auto stage = [&](int kt) {
        #pragma unroll
        for (int i = 0; i < 4; ++i) {
            int c    = i * 256 + tid;
            int row  = c >> 3;
            int slot = (c & 7) ^ (row & 7);
            const u16* ga = A  + (size_t)(rowA0 + row) * K + kt * 64 + slot * 8;
            const u16* gb = Bt + (size_t)(colB0 + row) * K + kt * 64 + slot * 8;
            int ldsOff = i * 4096 + wid * 1024;
            __builtin_amdgcn_global_load_lds((gu32*)ga, (su32*)(smem + ldsOff),         16, 0, 0);
            __builtin_amdgcn_global_load_lds((gu32*)gb, (su32*)(smem + 16384 + ldsOff), 16, 0, 0);
        }
    };

    f32x4 acc[4][4];
    #pragma unroll
    for (int m = 0; m < 4; ++m)
        #pragma unroll
        for (int n = 0; n < 4; ++n) acc[m][n] = f32x4{0.f, 0.f, 0.f, 0.f};

    for (int kt = 0; kt < KT; ++kt) {
        stage(kt);
        __syncthreads();
        #pragma unroll
        for (int ks = 0; ks < 2; ++ks) {
            bf16x8 af[4], bfr[4];
            #pragma unroll
            for (int m = 0; m < 4; ++m) {
                int row = wm * 64 + m * 16 + lr;
                int kbyte = (ks * 64 + hi * 16) ^ ((row & 7) << 4);
                af[m] = *(const bf16x8*)(smem + row * 128 + kbyte);
            }
            #pragma unroll
            for (int n = 0; n < 4; ++n) {
                int row = wn * 64 + n * 16 + lr;
                int kbyte = (ks * 64 + hi * 16) ^ ((row & 7) << 4);
                bfr[n] = *(const bf16x8*)(smem + 16384 + row * 128 + kbyte);
            }
            #pragma unroll
            for (int m = 0; m < 4; ++m)
                #pragma unroll
                for (int n = 0; n < 4; ++n)
                    acc[m][n] = __builtin_amdgcn_mfma_f32_16x16x32_bf16(af[m], bfr[n], acc[m][n], 0, 0, 0);
        }
        __syncthreads();
    }

    #pragma unroll
    for (int m = 0; m < 4; ++m) {
        #pragma unroll
        for (int n = 0; n < 4; ++n) {
            int gcol = colB0 + wn * 64 + n * 16 + lr;
            #pragma unroll
            for (int r = 0; r < 4; ++r) {
                int grow = rowA0 + wm * 64 + m * 16 + hi * 4 + r;
                float v = acc[m][n][r];
                if constexpr (EPI == 0) {
                    v = tanhf(v + bias[gcol]);
                } else {
                    v = v + bias[gcol] + resid[(size_t)grow * ldOut + gcol];
                }
                outB[(size_t)grow * ldOut + gcol] = f2bf(v);
            }
        }
    }
}

// ---------------- head GEMM: 128x256x64, 8 waves, SINGLE-buffer 48KB, 3 blocks/CU ---
// m97-style serial K-loop: stage -> sync -> compute -> sync. Co-resident blocks hide
// the vmcnt(0) drain and the epilogue store burst. Aligned nt-vector epilogue.
__global__ __launch_bounds__(512, 2)
void head_kernel(const u16* __restrict__ A, const u16* __restrict__ Bt,
                 const float* __restrict__ bias, float* __restrict__ outF,
                 int colStart, int nbx)
{
    __shared__ char smem[49152];            // A 16KB @0, B 32KB @16384; epilogue reuses
    const int tid  = threadIdx.x;
    const int wid  = tid >> 6;
    const int lane = tid & 63;
    const int wm   = wid >> 2, wn = wid & 3;
    const int lr   = lane & 15;
    const int hi   = lane >> 4;

    // block mapping: bijective XCD chunks, by-fastest (B-panel L2-resident)
    const int nwg = nbx * 64;
    const int per = nwg >> 3;               // nwg % 8 == 0
    const int wg  = (blockIdx.x & 7) * per + (blockIdx.x >> 3);
    const int bx  = wg >> 6;
    const int by  = wg & 63;
    const int rowA0 = by * 128;
    const int colB0 = bx * 256;

    f32x4 acc[4][4];
    #pragma unroll
    for (int m = 0; m < 4; ++m)
        #pragma unroll
        for (int n = 0; n < 4; ++n) acc[m][n] = f32x4{0.f, 0.f, 0.f, 0.f};

    for (int kt = 0; kt < 8; ++kt) {
        // ---- stage tile kt (A: 1024 units, B: 2048 units of 16B) ----
        #pragma unroll
        for (int i = 0; i < 2; ++i) {
            int u = i * 512 + tid;
            int row = u >> 3, slot = (u & 7) ^ (row & 7);
            const u16* ga = A + (size_t)(rowA0 + row) * C_ + kt * 64 + slot * 8;
            __builtin_amdgcn_global_load_lds((gu32*)ga, (su32*)(smem + i * 8192 + wid * 1024), 16, 0, 0);
        }
        #pragma unroll
        for (int i = 0; i < 4; ++i) {
            int u = i * 512 + tid;
            int row = u >> 3, slot = (u & 7) ^ (row & 7);
            const u16* gb = Bt + (size_t)(colB0 + row) * C_ + kt * 64 + slot * 8;
            __builtin_amdgcn_global_load_lds((gu32*)gb, (su32*)(smem + 16384 + i * 8192 + wid * 1024), 16, 0, 0);
        }
        __syncthreads();                    // vmcnt(0)+lgkmcnt(0) drain + barrier
        #pragma unroll
        for (int ks = 0; ks < 2; ++ks) {
            bf16x8 af[4], bfr[4];
            #pragma unroll
            for (int m = 0; m < 4; ++m) {
                int row = wm * 64 + m * 16 + lr;
                int kbyte = (ks * 64 + hi * 16) ^ ((row & 7) << 4);
                af[m] = *(const bf16x8*)(smem + row * 128 + kbyte);
            }
            #pragma unroll
            for (int n = 0; n < 4; ++n) {
                int row = wn * 64 + n * 16 + lr;
                int kbyte = (ks * 64 + hi * 16) ^ ((row & 7) << 4);
                bfr[n] = *(const bf16x8*)(smem + 16384 + row * 128 + kbyte);
            }
            #pragma unroll
            for (int m = 0; m < 4; ++m)
                #pragma unroll
                for (int n = 0; n < 4; ++n)
                    acc[m][n] = __builtin_amdgcn_mfma_f32_16x16x32_bf16(af[m], bfr[n], acc[m][n], 0, 0, 0);
        }
        __syncthreads();                    // LDS reads done before next stage
    }

    // ---- epilogue: 4 passes of 32 rows x 256 cols, LDS-staged, 16B-aligned stores --
    float* ebuf = (float*)smem;             // 32 x 264 floats = 33.8KB
    float biasr[4];
    #pragma unroll
    for (int nf = 0; nf < 4; ++nf) {
        int vc = colStart + colB0 + wn * 64 + nf * 16 + lr;
        biasr[nf] = (vc < V_) ? bias[vc] : 0.f;
    }
    const int er2 = tid >> 4;               // 0..31: output row owner
    const int kk  = tid & 15;
    #pragma unroll
    for (int mf = 0; mf < 4; ++mf) {
        __builtin_amdgcn_s_barrier();
        #pragma unroll
        for (int nf = 0; nf < 4; ++nf) {
            int ec = wn * 64 + nf * 16 + lr;
            int er = wm * 16 + hi * 4;
            #pragma unroll
            for (int r = 0; r < 4; ++r)
                ebuf[(er + r) * 264 + ec] = acc[mf][nf][r] + biasr[nf];
        }
        asm volatile("s_waitcnt lgkmcnt(0)" ::: "memory");
        __builtin_amdgcn_s_barrier();
        long grow = rowA0 + (er2 >> 4) * 64 + mf * 16 + (er2 & 15);
        long S    = grow * V_ + colStart + colB0;   // f32 flat index of col 0
        long a0   = (S + 3) & ~3L;                  // 16B-aligned start
        int  sh   = (int)(a0 - S);                  // 0..3
        const float* rowp = ebuf + er2 * 264;
        if (kk == 0) {
            for (int e = 0; e < sh; ++e) {          // head elems (cached: L2 merge)
                int vc = colStart + colB0 + e;
                if (vc < V_) outF[S + e] = rowp[e];
            }
        }
        #pragma unroll
        for (int j = 0; j < 4; ++j) {
            int  cb = sh + (kk + j * 16) * 4;       // block-local col of chunk
            long g  = a0 + (long)(kk + j * 16) * 4;
            int  vc = colStart + colB0 + cb;        // vocab col of first elem
            if (cb + 3 <= 255 && vc + 3 < V_) {
                f32x4a t = { rowp[cb], rowp[cb + 1], rowp[cb + 2], rowp[cb + 3] };
                __builtin_nontemporal_store(t, (f32x4a*)(outF + g));
            } else {
                #pragma unroll
                for (int e = 0; e < 4; ++e)
                    if (cb + e <= 255 && vc + e < V_)
                        outF[g + e] = rowp[cb + e];  // cached boundary stores
            }
        }
    }
}

// ------------------------------------------------------------------------------------
extern "C" void kernel_launch(void* const* d_in, const int* in_sizes, int n_in,
                              void* d_out, int out_size, void* d_ws, size_t ws_size,
                              hipStream_t stream)
{
    const int*   x      = (const int*)  d_in[0];
    const float* wte    = (const float*)d_in[1];
    const float* wpe    = (const float*)d_in[2];
    const float* w_fc   = (const float*)d_in[3];
    const float* b_fc   = (const float*)d_in[4];
    const float* w_proj = (const float*)d_in[5];
    const float* b_proj = (const float*)d_in[6];
    const float* w_head = (const float*)d_in[7];
    const float* b_head = (const float*)d_in[8];
    float* out = (float*)d_out;

    // Scratch inside d_out (dead before the head GEMM overwrites d_out)
    char*  ob   = (char*)d_out;
    float* emb  = (float*)(ob);                    // 16 MB
    float* h1f  = (float*)(ob + 16 * MB_);         // 16 MB
    u16*   h1b  = (u16*)  (ob + 32 * MB_);         //  8 MB
    u16*   actb = (u16*)  (ob + 40 * MB_);         // 32 MB
    u16*   wfct = (u16*)  (ob + 72 * MB_);         //  2 MB
    u16*   wprt = (u16*)  (ob + 74 * MB_);         //  2 MB
    float* S    = (float*)(ob + 76 * MB_);         // 128 KB
    float* P    = (float*)(ob + 76 * MB_ + 128 * 1024);

    // ws: only what must survive while the head GEMM writes d_out
    u16* h2b = (u16*)d_ws;                         // 8 MB
    u16* wht = (u16*)((char*)d_ws + 8 * MB_);      // head weight chunk (bf16, transposed)

    long availCols = 0;
    if (ws_size > 8 * MB_ + 512 * 1024)
        availCols = (long)((ws_size - 8 * MB_) / (C_ * 2));
    int chunk = (int)(availCols & ~255L);
    if (chunk < 256)   chunk = 256;
    if (chunk > VPAD_) chunk = VPAD_;

    // weights -> bf16 transposed (N-major, K-contiguous)
    tconv_kernel<<<dim3(H_ / 32, C_ / 32), dim3(32, 8), 0, stream>>>(w_fc,   wfct, C_, H_, 0, H_);
    tconv_kernel<<<dim3(C_ / 32, H_ / 32), dim3(32, 8), 0, stream>>>(w_proj, wprt, H_, C_, 0, C_);

    // embedding + causal BoW
    emb_kernel <<<128, 256, 0, stream>>>(x, wte, wpe, emb, S);
    scan_kernel<<<8,   256, 0, stream>>>(S, P);
    bow_kernel <<<128, 256, 0, stream>>>(emb, P, h1f, h1b);

    // MLP
    gemm_kernel<0><<<(H_ / 128) * (BT_ / 128), 256, 0, stream>>>(
        h1b, wfct, BT_, H_, C_, b_fc, nullptr, actb, H_);
    gemm_kernel<1><<<(C_ / 128) * (BT_ / 128), 256, 0, stream>>>(
        actb, wprt, BT_, C_, H_, b_proj, h1f, h2b, C_);

    // head: V processed in ws-sized column chunks
    for (int cs = 0; cs < VPAD_; cs += chunk) {
        int nc = VPAD_ - cs < chunk ? VPAD_ - cs : chunk;
        tconv_kernel<<<dim3(nc / 32, C_ / 32), dim3(32, 8), 0, stream>>>(
            w_head, wht, C_, V_, cs, nc);
        head_kernel<<<(nc / 256) * 64, 512, 0, stream>>>(
            h2b, wht, b_head, out, cs, nc / 256);
    }
}